// Round 11
// baseline (218.299 us; speedup 1.0000x reference)
//
#include <hip/hip_runtime.h>
#include <hip/hip_bf16.h>
#include <stdint.h>

#define DEVI __device__ __forceinline__

typedef __attribute__((ext_vector_type(8))) short s8v;   // 8 bf16 MFMA A/B frag
typedef __attribute__((ext_vector_type(4))) float f4v;   // MFMA C/D frag
typedef __attribute__((ext_vector_type(4))) int i4v;     // 16B LDS read
typedef unsigned short u16;

// ---------- helpers ----------
DEVI float bf2f(u16 u) { union { uint32_t i; float f; } c; c.i = ((uint32_t)u) << 16; return c.f; }
DEVI u16 f2bf(float f) {
  union { float f; uint32_t u; } c; c.f = f;
  uint32_t u = c.u;
  u += 0x7fffu + ((u >> 16) & 1u);   // RNE
  return (u16)(u >> 16);
}

DEVI void gld16(const void* g, void* l) {
  auto gp = reinterpret_cast<const __attribute__((address_space(1))) void*>(reinterpret_cast<uintptr_t>(g));
  auto lp = reinterpret_cast<__attribute__((address_space(3))) void*>(reinterpret_cast<uintptr_t>(l));
  __builtin_amdgcn_global_load_lds(gp, lp, 16, 0, 0);
}

DEVI float wredsum(float v) {
  #pragma unroll
  for (int o = 32; o; o >>= 1) v += __shfl_xor(v, o);
  return v;
}

#define MFMA16(a, b, c) __builtin_amdgcn_mfma_f32_16x16x32_bf16((a), (b), (c), 0, 0, 0)

// out[c][r] = (bf16) in[r][c];  in is [R][C], out is [C][R].  z batches.
__global__ void transpose_cvt(const float* __restrict__ in, u16* __restrict__ out, int R, int C) {
  __shared__ float t[32][33];
  in  += (size_t)blockIdx.z * R * C;
  out += (size_t)blockIdx.z * R * C;
  int r0 = blockIdx.y * 32, c0 = blockIdx.x * 32;
  int tx = threadIdx.x, ty = threadIdx.y;
  #pragma unroll
  for (int j = ty; j < 32; j += 8) t[j][tx] = in[(size_t)(r0 + j) * C + c0 + tx];
  __syncthreads();
  #pragma unroll
  for (int j = ty; j < 32; j += 8) out[(size_t)(c0 + j) * R + r0 + tx] = f2bf(t[tx][j]);
}

// ================= 128^2 GEMM, 4 waves =================
// D row = 4*(lane>>4)+v, col = lane&15 (m89-verified layout)

// read 8 f32 from swizzled f32 LDS tile (256B rows), convert -> bf16x8 frag
DEVI s8v cvt_frag(const char* base, int ra, int cb) {
  const int sa = (ra & 7) << 4;               // XOR byte-bits 4-6 (both-sides w/ staging)
  const char* rp = base + ra * 256;
  i4v lo = *(const i4v*)(rp + ((cb)      ^ sa));
  i4v hi = *(const i4v*)(rp + ((cb + 16) ^ sa));
  union { i4v v; float f[4]; } L, H; L.v = lo; H.v = hi;
  union { s8v v; __hip_bfloat162 h[4]; } R;
  R.h[0] = __float22bfloat162_rn(make_float2(L.f[0], L.f[1]));
  R.h[1] = __float22bfloat162_rn(make_float2(L.f[2], L.f[3]));
  R.h[2] = __float22bfloat162_rn(make_float2(H.f[0], H.f[1]));
  R.h[3] = __float22bfloat162_rn(make_float2(H.f[2], H.f[3]));
  return R.v;
}

// ---------- GEMM1: A = hidden (f32, staged raw via global_load_lds, cvt on read) ----------
// out bf16 = acc + bias[n];  part[tn*16384+m] = sum_{n in tile} out[m][n]*encW[n]
// (cvt_f32_bf16 pass eliminated; LDS 48KB -> 3 blocks/CU)
__global__ __launch_bounds__(256, 3) void gemm_bt1(
    const float* __restrict__ Af, const u16* __restrict__ Bt, u16* __restrict__ out,
    const float* __restrict__ bias, const float* __restrict__ encW, float* __restrict__ part)
{
  const int tid  = threadIdx.x;
  const int lane = tid & 63;
  const int wv   = tid >> 6;
  const int wg = ((blockIdx.x & 7) << 7) | (blockIdx.x >> 3);   // XCD-bijective swizzle
  const int tm = wg >> 3;
  const int tn = wg & 7;

  __shared__ char As[32768];                  // 128 x 64 f32 (256B rows)
  __shared__ char Bs[16384];                  // 128 x 64 bf16 (128B rows)
  __shared__ float redbuf[128];

  f4v acc[4][4];
  #pragma unroll
  for (int i = 0; i < 4; i++)
    #pragma unroll
    for (int j = 0; j < 4; j++) acc[i][j] = f4v{0.f, 0.f, 0.f, 0.f};

  const int wr = wv >> 1, wc = wv & 1;
  const int mB = wr * 64, nB = wc * 64;
  const int fr = lane & 15;
  const int fkbyte = (lane >> 4) << 4;        // bf16-side 16B k-offset (B frags)
  const int fkf32  = (lane >> 4) << 5;        // f32-side 32B k-offset (A frags)

  const char* Ab = (const char*)(Af + (size_t)tm * 128 * 1024);
  const char* Bb = (const char*)(Bt + (size_t)tn * 128 * 1024);

  for (int k0 = 0; k0 < 1024; k0 += 64) {
    // B: bf16, 4 x 16B per thread, 128B rows, XOR bits 4-6? (<<4 on 128B rows = bits 4-6)
    #pragma unroll
    for (int c = 0; c < 4; ++c) {
      int p = wv * 1024 + lane * 16 + c * 4096;
      int row = p >> 7;
      int kb = (p & 127) ^ ((row & 7) << 4);
      gld16(Bb + (size_t)row * 2048 + k0 * 2 + kb, Bs + p);
    }
    // A: f32, 8 x 16B per thread, 256B rows, inverse-swizzled source, linear LDS dest
    #pragma unroll
    for (int c = 0; c < 8; ++c) {
      int p = tid * 16 + c * 4096;
      int row = p >> 8;
      int kb = (p & 255) ^ ((row & 7) << 4);
      gld16(Ab + (size_t)row * 4096 + k0 * 4 + kb, As + p);
    }
    __syncthreads();
    #pragma unroll
    for (int kk = 0; kk < 2; ++kk) {
      s8v af[4], bf[4];
      #pragma unroll
      for (int i = 0; i < 4; ++i) {
        af[i] = cvt_frag(As, mB + i * 16 + fr, kk * 128 + fkf32);
        int rb = nB + i * 16 + fr;
        int kbyte = kk * 64 + fkbyte;
        bf[i] = *(const s8v*)(Bs + rb * 128 + (kbyte ^ ((rb & 7) << 4)));
      }
      #pragma unroll
      for (int mi = 0; mi < 4; ++mi)
        #pragma unroll
        for (int ni = 0; ni < 4; ++ni)
          acc[mi][ni] = MFMA16(af[mi], bf[ni], acc[mi][ni]);
    }
    __syncthreads();
  }

  const int mBase = tm * 128 + mB;
  const int nBase = tn * 128 + nB;
  const int rl = (lane >> 4) << 2;
  const int cl = lane & 15;
  float ew[4], bv[4];
  #pragma unroll
  for (int ni = 0; ni < 4; ++ni) {
    ew[ni] = encW[nBase + ni * 16 + cl];
    bv[ni] = bias[nBase + ni * 16 + cl];
  }
  float md[4][4];
  #pragma unroll
  for (int mi = 0; mi < 4; ++mi) {
    #pragma unroll
    for (int v = 0; v < 4; ++v) {
      int m = mBase + mi * 16 + rl + v;
      float dotp = 0.f;
      #pragma unroll
      for (int ni = 0; ni < 4; ++ni) {
        int n = nBase + ni * 16 + cl;
        float val = acc[mi][ni][v] + bv[ni];
        out[(size_t)m * 1024 + n] = f2bf(val);
        dotp += val * ew[ni];
      }
      #pragma unroll
      for (int o = 1; o < 16; o <<= 1) dotp += __shfl_xor(dotp, o);
      md[mi][v] = dotp;
      if (wc == 0 && cl == 0) redbuf[mB + mi * 16 + rl + v] = dotp;
    }
  }
  __syncthreads();
  if (wc == 1 && cl == 0) {
    #pragma unroll
    for (int mi = 0; mi < 4; ++mi)
      #pragma unroll
      for (int v = 0; v < 4; ++v) {
        int ml = mB + mi * 16 + rl + v;
        part[(size_t)tn * 16384 + tm * 128 + ml] = redbuf[ml] + md[mi][v];
      }
  }
}

// ---------- GEMM2/3 (r2-proven, unchanged) ----------
// EPI 2: out bf16 = e1[b*4+t] * (acc + e0[n])
// EPI 3: out bf16 = acc + e0[b*1024+n] + bf16(e2[idx]) + e1[idx]  (out aliases e2 same-index)
template<int EPI>
__global__ __launch_bounds__(256, 4) void gemm_bt(
    const u16* __restrict__ A, const u16* __restrict__ Bt, void* out,
    const float* __restrict__ e0, const float* __restrict__ e1, const u16* e2)
{
  const int tid  = threadIdx.x;
  const int lane = tid & 63;
  const int wv   = tid >> 6;
  const int wg = ((blockIdx.x & 7) << 7) | (blockIdx.x >> 3);   // XCD-bijective swizzle
  const int tm = wg >> 3;
  const int tn = wg & 7;

  __shared__ char lds[32768];
  char* As = lds;
  char* Bs = lds + 16384;

  f4v acc[4][4];
  #pragma unroll
  for (int i = 0; i < 4; i++)
    #pragma unroll
    for (int j = 0; j < 4; j++) acc[i][j] = f4v{0.f, 0.f, 0.f, 0.f};

  const int wr = wv >> 1, wc = wv & 1;
  const int mB = wr * 64, nB = wc * 64;
  const int fr = lane & 15;
  const int fkbyte = (lane >> 4) << 4;

  const char* Ab = (const char*)(A + (size_t)tm * 128 * 1024);
  const char* Bb = (const char*)(Bt + (size_t)tn * 128 * 1024);

  for (int k0 = 0; k0 < 1024; k0 += 64) {
    #pragma unroll
    for (int c = 0; c < 4; ++c) {
      int p = wv * 1024 + lane * 16 + c * 4096;
      int row = p >> 7;
      int kb = (p & 127) ^ ((row & 7) << 4);
      gld16(Ab + (size_t)row * 2048 + k0 * 2 + kb, As + p);
      gld16(Bb + (size_t)row * 2048 + k0 * 2 + kb, Bs + p);
    }
    __syncthreads();
    #pragma unroll
    for (int kk = 0; kk < 2; ++kk) {
      s8v af[4], bf[4];
      #pragma unroll
      for (int i = 0; i < 4; ++i) {
        int ra = mB + i * 16 + fr;
        int rb = nB + i * 16 + fr;
        int kbyte = kk * 64 + fkbyte;
        af[i] = *(const s8v*)(As + ra * 128 + (kbyte ^ ((ra & 7) << 4)));
        bf[i] = *(const s8v*)(Bs + rb * 128 + (kbyte ^ ((rb & 7) << 4)));
      }
      #pragma unroll
      for (int mi = 0; mi < 4; ++mi)
        #pragma unroll
        for (int ni = 0; ni < 4; ++ni)
          acc[mi][ni] = MFMA16(af[mi], bf[ni], acc[mi][ni]);
    }
    __syncthreads();
  }

  const int mBase = tm * 128 + mB;
  const int nBase = tn * 128 + nB;
  const int rl = (lane >> 4) << 2;
  const int cl = lane & 15;
  float scale = 0.f;
  const float* b2row = nullptr;
  if constexpr (EPI == 2) scale = e1[(tm >> 4) * 4 + (tn >> 1)];
  if constexpr (EPI == 3) b2row = e0 + (tm >> 4) * 1024;

  #pragma unroll
  for (int mi = 0; mi < 4; ++mi) {
    #pragma unroll
    for (int ni = 0; ni < 4; ++ni) {
      int n = nBase + ni * 16 + cl;
      #pragma unroll
      for (int v = 0; v < 4; ++v) {
        int m = mBase + mi * 16 + rl + v;
        size_t idx = (size_t)m * 1024 + n;
        float val = acc[mi][ni][v];
        if constexpr (EPI == 2) {
          ((u16*)out)[idx] = f2bf(scale * (val + e0[n]));
        } else {
          ((u16*)out)[idx] = f2bf(val + b2row[n] + bf2f(e2[idx]) + e1[idx]);
        }
      }
    }
  }
}

// ---------- per-batch softmax over S=2048; logits = sum of 8 partials (fixed order) ----------
__global__ void softmax_seq(const float* __restrict__ part, const float* __restrict__ mask,
                            float* __restrict__ w) {
  int b = blockIdx.x, tid = threadIdx.x;
  int lane = tid & 63, wv = tid >> 6;
  const float* mp = mask + (size_t)b * 2048;
  float v[8];
  #pragma unroll
  for (int i = 0; i < 8; i++) {
    int row = b * 2048 + tid * 8 + i;
    float s = 0.f;
    #pragma unroll
    for (int t = 0; t < 8; t++) s += part[(size_t)t * 16384 + row];
    v[i] = s + mp[tid * 8 + i];
  }
  float mx = -1e30f;
  #pragma unroll
  for (int i = 0; i < 8; i++) mx = fmaxf(mx, v[i]);
  __shared__ float red[4];
  #pragma unroll
  for (int o = 32; o; o >>= 1) mx = fmaxf(mx, __shfl_xor(mx, o));
  if (lane == 0) red[wv] = mx;
  __syncthreads();
  mx = fmaxf(fmaxf(red[0], red[1]), fmaxf(red[2], red[3]));
  __syncthreads();
  float s = 0.f;
  #pragma unroll
  for (int i = 0; i < 8; i++) { v[i] = expf(v[i] - mx); s += v[i]; }
  s = wredsum(s);
  if (lane == 0) red[wv] = s;
  __syncthreads();
  s = red[0] + red[1] + red[2] + red[3];
  float inv = 1.f / s;
  #pragma unroll
  for (int i = 0; i < 8; i++) w[(size_t)b * 2048 + tid * 8 + i] = v[i] * inv;
}

// ---------- tvp[b][sc][col] = sum_{s in chunk sc} w[b][s] * h[b][s][col] ----------
__global__ void taskvec_part(const u16* __restrict__ h, const float* __restrict__ w,
                             float* __restrict__ tvp) {
  int b = blockIdx.y, sc = blockIdx.z;
  int col = blockIdx.x * 256 + threadIdx.x;
  const u16* hp = h + ((size_t)b * 2048 + sc * 256) * 1024 + col;
  const float* wp = w + (size_t)b * 2048 + sc * 256;
  float a0 = 0.f, a1 = 0.f, a2 = 0.f, a3 = 0.f;
  for (int s = 0; s < 256; s += 4) {
    a0 += wp[s]     * bf2f(hp[(size_t)s * 1024]);
    a1 += wp[s + 1] * bf2f(hp[(size_t)(s + 1) * 1024]);
    a2 += wp[s + 2] * bf2f(hp[(size_t)(s + 2) * 1024]);
    a3 += wp[s + 3] * bf2f(hp[(size_t)(s + 3) * 1024]);
  }
  tvp[((size_t)b * 8 + sc) * 1024 + col] = (a0 + a1) + (a2 + a3);
}

// ---------- merged: reduce tvp -> tv (LDS) -> d[b][t] softmax -> bias2 ----------
__global__ void taskvec_dist(const float* __restrict__ tvp, const float* __restrict__ selW,
                             const float* __restrict__ selb, const float* __restrict__ pb2,
                             float* __restrict__ dvec, float* __restrict__ bias2) {
  int b = blockIdx.x, tid = threadIdx.x;
  int lane = tid & 63, wv = tid >> 6;
  __shared__ float tvs[1024];
  #pragma unroll
  for (int c4 = 0; c4 < 4; ++c4) {
    int col = c4 * 256 + tid;
    float s = 0.f;
    #pragma unroll
    for (int c = 0; c < 8; ++c) s += tvp[((size_t)b * 8 + c) * 1024 + col];
    tvs[col] = s;
  }
  __syncthreads();
  const float* sw = selW + (size_t)wv * 1024;
  float s = 0.f;
  #pragma unroll
  for (int j = 0; j < 16; j++) s += tvs[lane * 16 + j] * sw[lane * 16 + j];
  s = wredsum(s);
  __shared__ float lg[4];
  if (lane == 0) lg[wv] = s + selb[wv];
  __syncthreads();
  float m = fmaxf(fmaxf(lg[0], lg[1]), fmaxf(lg[2], lg[3]));
  float e0 = expf(lg[0] - m), e1 = expf(lg[1] - m), e2 = expf(lg[2] - m), e3 = expf(lg[3] - m);
  float inv = 1.f / (e0 + e1 + e2 + e3);
  float d0 = e0 * inv, d1 = e1 * inv, d2 = e2 * inv, d3 = e3 * inv;
  if (tid < 4) dvec[b * 4 + tid] = (tid == 0) ? d0 : (tid == 1) ? d1 : (tid == 2) ? d2 : d3;
  #pragma unroll
  for (int c = 0; c < 4; c++) {
    int n = c * 256 + tid;
    bias2[(size_t)b * 1024 + n] =
        d0 * pb2[n] + d1 * pb2[1024 + n] + d2 * pb2[2048 + n] + d3 * pb2[3072 + n];
  }
}

// ---------- row LayerNorm (H=1024) from bf16 x -> f32 out ----------
__global__ void ln_bf16_kernel(const u16* __restrict__ x, const float* __restrict__ g,
                               const float* __restrict__ bt, float* __restrict__ out) {
  int row = blockIdx.x, tid = threadIdx.x;
  int lane = tid & 63, wv = tid >> 6;
  ushort4 u = ((const ushort4*)(x + (size_t)row * 1024))[tid];
  float v0 = bf2f(u.x), v1 = bf2f(u.y), v2 = bf2f(u.z), v3 = bf2f(u.w);
  float s = v0 + v1 + v2 + v3;
  float q = v0 * v0 + v1 * v1 + v2 * v2 + v3 * v3;
  #pragma unroll
  for (int o = 32; o; o >>= 1) { s += __shfl_xor(s, o); q += __shfl_xor(q, o); }
  __shared__ float rs[4], rq[4];
  if (lane == 0) { rs[wv] = s; rq[wv] = q; }
  __syncthreads();
  s = rs[0] + rs[1] + rs[2] + rs[3];
  q = rq[0] + rq[1] + rq[2] + rq[3];
  float mu = s * (1.f / 1024.f);
  float var = q * (1.f / 1024.f) - mu * mu;
  float inv = 1.f / sqrtf(var + 1e-12f);
  const float4 gv = ((const float4*)g)[tid];
  const float4 bv = ((const float4*)bt)[tid];
  float4 o;
  o.x = gv.x * (v0 - mu) * inv + bv.x;
  o.y = gv.y * (v1 - mu) * inv + bv.y;
  o.z = gv.z * (v2 - mu) * inv + bv.z;
  o.w = gv.w * (v3 - mu) * inv + bv.w;
  ((float4*)(out + (size_t)row * 1024))[tid] = o;
}

extern "C" void kernel_launch(void* const* d_in, const int* in_sizes, int n_in,
                              void* d_out, int out_size, void* d_ws, size_t ws_size,
                              hipStream_t stream) {
  const float* hidden = (const float*)d_in[0];
  const float* input  = (const float*)d_in[1];
  const float* mask   = (const float*)d_in[2];
  const float* denseW = (const float*)d_in[3];
  const float* denseB = (const float*)d_in[4];
  const float* palW1  = (const float*)d_in[5];
  const float* palB1  = (const float*)d_in[6];
  const float* palW2  = (const float*)d_in[7];
  const float* palB2  = (const float*)d_in[8];
  const float* encW   = (const float*)d_in[9];
  const float* selW   = (const float*)d_in[11];
  const float* selB   = (const float*)d_in[12];
  const float* lnG    = (const float*)d_in[13];
  const float* lnB    = (const float*)d_in[14];

  char* ws = (char*)d_ws;
  u16*  hbf    = (u16*)(ws);                       // 32 MB  h (bf16), later x (bf16, in-place)
  u16*  lowbuf = (u16*)(ws + 33554432);            // 32 MB  low (scaled), GEMM2 out / GEMM3 in
  u16*  wdt    = (u16*)(ws + 67108864);            // 2 MB   dense_W^T
  u16*  w1t    = (u16*)(ws + 69206016);            // 2 MB   W1cat^T  [(t,p)][h]
  u16*  w2t    = (u16*)(ws + 71303168);            // 2 MB   W2cat^T  [h][(t,p)]
  float* wts    = (float*)(ws + 73465856);
  float* dvec   = (float*)(ws + 73564160);
  float* bias2  = (float*)(ws + 73568256);
  float* tvp    = (float*)(ws + 73601024);         // 256 KB partials

  // logits partials live in d_out scratch (fully written by gemm_bt1, consumed by
  // softmax, overwritten by LN at the end)
  float* lgpart = (float*)d_out;                   // 8 x 16384 f32 = 512 KB

  transpose_cvt<<<dim3(32, 32, 1), dim3(32, 8), 0, stream>>>(denseW, wdt, 1024, 1024);
  transpose_cvt<<<dim3(8, 32, 4),  dim3(32, 8), 0, stream>>>(palW1, w1t, 1024, 256);
  transpose_cvt<<<dim3(32, 32, 1), dim3(32, 8), 0, stream>>>(palW2, w2t, 1024, 1024);

  // GEMM1 reads hidden (f32) directly -- cvt pass eliminated
  gemm_bt1<<<1024, 256, 0, stream>>>(hidden, wdt, hbf, denseB, encW, lgpart);

  softmax_seq<<<8, 256, 0, stream>>>(lgpart, mask, wts);
  taskvec_part<<<dim3(4, 8, 8), 256, 0, stream>>>(hbf, wts, tvp);
  taskvec_dist<<<8, 256, 0, stream>>>(tvp, selW, selB, palB2, dvec, bias2);

  gemm_bt<2><<<1024, 256, 0, stream>>>(hbf, w1t, lowbuf, palB1, dvec, nullptr);
  gemm_bt<3><<<1024, 256, 0, stream>>>(lowbuf, w2t, hbf, bias2, input, hbf);

  ln_bf16_kernel<<<16384, 256, 0, stream>>>(hbf, lnG, lnB, (float*)d_out);
}

// Round 12
// 201.072 us; speedup vs baseline: 1.0857x; 1.0857x over previous
//
#include <hip/hip_runtime.h>
#include <stdint.h>

#define DEVI __device__ __forceinline__

typedef __attribute__((ext_vector_type(8))) short s8v;   // 8 bf16 MFMA A/B frag
typedef __attribute__((ext_vector_type(4))) float f4v;   // MFMA C/D frag
typedef unsigned short u16;

// ---------- helpers ----------
DEVI float bf2f(u16 u) { union { uint32_t i; float f; } c; c.i = ((uint32_t)u) << 16; return c.f; }
DEVI u16 f2bf(float f) {
  union { float f; uint32_t u; } c; c.f = f;
  uint32_t u = c.u;
  u += 0x7fffu + ((u >> 16) & 1u);   // RNE
  return (u16)(u >> 16);
}

DEVI void gld16(const void* g, void* l) {
  auto gp = reinterpret_cast<const __attribute__((address_space(1))) void*>(reinterpret_cast<uintptr_t>(g));
  auto lp = reinterpret_cast<__attribute__((address_space(3))) void*>(reinterpret_cast<uintptr_t>(l));
  __builtin_amdgcn_global_load_lds(gp, lp, 16, 0, 0);
}

DEVI float wredsum(float v) {
  #pragma unroll
  for (int o = 32; o; o >>= 1) v += __shfl_xor(v, o);
  return v;
}

#define MFMA16(a, b, c) __builtin_amdgcn_mfma_f32_16x16x32_bf16((a), (b), (c), 0, 0, 0)

// ---------- conversions ----------
__global__ void cvt_f32_bf16(const float4* __restrict__ in, ushort4* __restrict__ out) {
  int i = blockIdx.x * 256 + threadIdx.x;
  float4 v = in[i];
  ushort4 o;
  o.x = f2bf(v.x); o.y = f2bf(v.y); o.z = f2bf(v.z); o.w = f2bf(v.w);
  out[i] = o;
}

// out[c][r] = (bf16) in[r][c];  in is [R][C], out is [C][R].  z batches.
__global__ void transpose_cvt(const float* __restrict__ in, u16* __restrict__ out, int R, int C) {
  __shared__ float t[32][33];
  in  += (size_t)blockIdx.z * R * C;
  out += (size_t)blockIdx.z * R * C;
  int r0 = blockIdx.y * 32, c0 = blockIdx.x * 32;
  int tx = threadIdx.x, ty = threadIdx.y;
  #pragma unroll
  for (int j = ty; j < 32; j += 8) t[j][tx] = in[(size_t)(r0 + j) * C + c0 + tx];
  __syncthreads();
  #pragma unroll
  for (int j = ty; j < 32; j += 8) out[(size_t)(c0 + j) * R + r0 + tx] = f2bf(t[tx][j]);
}

// ================= r2-proven 128^2 GEMM, 4 waves, launch_bounds(256,4) =================
// D row = 4*(lane>>4)+v, col = lane&15 (m89-verified layout)

// ---------- GEMM1: EPI1 + fused deterministic rowdot partials ----------
// out bf16 = acc + bias[n];  part[tn*16384+m] = sum_{n in this 128-tile} out[m][n]*encW[n]
// wc=0 wave writes its 64-col half to LDS; wc=1 wave adds its half, single store. No atomics.
__global__ __launch_bounds__(256, 4) void gemm_bt1(
    const u16* __restrict__ A, const u16* __restrict__ Bt, u16* __restrict__ out,
    const float* __restrict__ bias, const float* __restrict__ encW, float* __restrict__ part)
{
  const int tid  = threadIdx.x;
  const int lane = tid & 63;
  const int wv   = tid >> 6;
  const int wg = ((blockIdx.x & 7) << 7) | (blockIdx.x >> 3);   // XCD-bijective swizzle
  const int tm = wg >> 3;
  const int tn = wg & 7;

  __shared__ char lds[32768];
  char* As = lds;
  char* Bs = lds + 16384;
  __shared__ float redbuf[128];

  f4v acc[4][4];
  #pragma unroll
  for (int i = 0; i < 4; i++)
    #pragma unroll
    for (int j = 0; j < 4; j++) acc[i][j] = f4v{0.f, 0.f, 0.f, 0.f};

  const int wr = wv >> 1, wc = wv & 1;
  const int mB = wr * 64, nB = wc * 64;
  const int fr = lane & 15;
  const int fkbyte = (lane >> 4) << 4;

  const char* Ab = (const char*)(A + (size_t)tm * 128 * 1024);
  const char* Bb = (const char*)(Bt + (size_t)tn * 128 * 1024);

  for (int k0 = 0; k0 < 1024; k0 += 64) {
    #pragma unroll
    for (int c = 0; c < 4; ++c) {
      int p = wv * 1024 + lane * 16 + c * 4096;
      int row = p >> 7;
      int kb = (p & 127) ^ ((row & 7) << 4);
      gld16(Ab + (size_t)row * 2048 + k0 * 2 + kb, As + p);
      gld16(Bb + (size_t)row * 2048 + k0 * 2 + kb, Bs + p);
    }
    __syncthreads();
    #pragma unroll
    for (int kk = 0; kk < 2; ++kk) {
      s8v af[4], bf[4];
      #pragma unroll
      for (int i = 0; i < 4; ++i) {
        int ra = mB + i * 16 + fr;
        int rb = nB + i * 16 + fr;
        int kbyte = kk * 64 + fkbyte;
        af[i] = *(const s8v*)(As + ra * 128 + (kbyte ^ ((ra & 7) << 4)));
        bf[i] = *(const s8v*)(Bs + rb * 128 + (kbyte ^ ((rb & 7) << 4)));
      }
      #pragma unroll
      for (int mi = 0; mi < 4; ++mi)
        #pragma unroll
        for (int ni = 0; ni < 4; ++ni)
          acc[mi][ni] = MFMA16(af[mi], bf[ni], acc[mi][ni]);
    }
    __syncthreads();
  }

  const int mBase = tm * 128 + mB;
  const int nBase = tn * 128 + nB;
  const int rl = (lane >> 4) << 2;
  const int cl = lane & 15;
  float ew[4], bv[4];
  #pragma unroll
  for (int ni = 0; ni < 4; ++ni) {
    ew[ni] = encW[nBase + ni * 16 + cl];
    bv[ni] = bias[nBase + ni * 16 + cl];
  }
  float md[4][4];
  #pragma unroll
  for (int mi = 0; mi < 4; ++mi) {
    #pragma unroll
    for (int v = 0; v < 4; ++v) {
      int m = mBase + mi * 16 + rl + v;
      float dotp = 0.f;
      #pragma unroll
      for (int ni = 0; ni < 4; ++ni) {
        int n = nBase + ni * 16 + cl;
        float val = acc[mi][ni][v] + bv[ni];
        out[(size_t)m * 1024 + n] = f2bf(val);
        dotp += val * ew[ni];
      }
      #pragma unroll
      for (int o = 1; o < 16; o <<= 1) dotp += __shfl_xor(dotp, o);
      md[mi][v] = dotp;
      if (wc == 0 && cl == 0) redbuf[mB + mi * 16 + rl + v] = dotp;
    }
  }
  __syncthreads();
  if (wc == 1 && cl == 0) {
    #pragma unroll
    for (int mi = 0; mi < 4; ++mi)
      #pragma unroll
      for (int v = 0; v < 4; ++v) {
        int ml = mB + mi * 16 + rl + v;
        part[(size_t)tn * 16384 + tm * 128 + ml] = redbuf[ml] + md[mi][v];
      }
  }
}

// ---------- GEMM2/3 (r2-proven) ----------
// EPI 2: out bf16 = e1[b*4+t] * (acc + e0[n])
// EPI 3: out bf16 = acc + e0[b*1024+n] + bf16(e2[idx]) + e1[idx]  (out aliases e2 same-index)
template<int EPI>
__global__ __launch_bounds__(256, 4) void gemm_bt(
    const u16* __restrict__ A, const u16* __restrict__ Bt, void* out,
    const float* __restrict__ e0, const float* __restrict__ e1, const u16* e2)
{
  const int tid  = threadIdx.x;
  const int lane = tid & 63;
  const int wv   = tid >> 6;
  const int wg = ((blockIdx.x & 7) << 7) | (blockIdx.x >> 3);   // XCD-bijective swizzle
  const int tm = wg >> 3;
  const int tn = wg & 7;

  __shared__ char lds[32768];
  char* As = lds;
  char* Bs = lds + 16384;

  f4v acc[4][4];
  #pragma unroll
  for (int i = 0; i < 4; i++)
    #pragma unroll
    for (int j = 0; j < 4; j++) acc[i][j] = f4v{0.f, 0.f, 0.f, 0.f};

  const int wr = wv >> 1, wc = wv & 1;
  const int mB = wr * 64, nB = wc * 64;
  const int fr = lane & 15;
  const int fkbyte = (lane >> 4) << 4;

  const char* Ab = (const char*)(A + (size_t)tm * 128 * 1024);
  const char* Bb = (const char*)(Bt + (size_t)tn * 128 * 1024);

  for (int k0 = 0; k0 < 1024; k0 += 64) {
    #pragma unroll
    for (int c = 0; c < 4; ++c) {
      int p = wv * 1024 + lane * 16 + c * 4096;
      int row = p >> 7;
      int kb = (p & 127) ^ ((row & 7) << 4);
      gld16(Ab + (size_t)row * 2048 + k0 * 2 + kb, As + p);
      gld16(Bb + (size_t)row * 2048 + k0 * 2 + kb, Bs + p);
    }
    __syncthreads();
    #pragma unroll
    for (int kk = 0; kk < 2; ++kk) {
      s8v af[4], bf[4];
      #pragma unroll
      for (int i = 0; i < 4; ++i) {
        int ra = mB + i * 16 + fr;
        int rb = nB + i * 16 + fr;
        int kbyte = kk * 64 + fkbyte;
        af[i] = *(const s8v*)(As + ra * 128 + (kbyte ^ ((ra & 7) << 4)));
        bf[i] = *(const s8v*)(Bs + rb * 128 + (kbyte ^ ((rb & 7) << 4)));
      }
      #pragma unroll
      for (int mi = 0; mi < 4; ++mi)
        #pragma unroll
        for (int ni = 0; ni < 4; ++ni)
          acc[mi][ni] = MFMA16(af[mi], bf[ni], acc[mi][ni]);
    }
    __syncthreads();
  }

  const int mBase = tm * 128 + mB;
  const int nBase = tn * 128 + nB;
  const int rl = (lane >> 4) << 2;
  const int cl = lane & 15;
  float scale = 0.f;
  const float* b2row = nullptr;
  if constexpr (EPI == 2) scale = e1[(tm >> 4) * 4 + (tn >> 1)];
  if constexpr (EPI == 3) b2row = e0 + (tm >> 4) * 1024;

  #pragma unroll
  for (int mi = 0; mi < 4; ++mi) {
    #pragma unroll
    for (int ni = 0; ni < 4; ++ni) {
      int n = nBase + ni * 16 + cl;
      #pragma unroll
      for (int v = 0; v < 4; ++v) {
        int m = mBase + mi * 16 + rl + v;
        size_t idx = (size_t)m * 1024 + n;
        float val = acc[mi][ni][v];
        if constexpr (EPI == 2) {
          ((u16*)out)[idx] = f2bf(scale * (val + e0[n]));
        } else {
          ((u16*)out)[idx] = f2bf(val + b2row[n] + bf2f(e2[idx]) + e1[idx]);
        }
      }
    }
  }
}

// ---------- per-batch softmax over S=2048; logits = sum of 8 partials (fixed order) ----------
__global__ void softmax_seq(const float* __restrict__ part, const float* __restrict__ mask,
                            float* __restrict__ w) {
  int b = blockIdx.x, tid = threadIdx.x;
  int lane = tid & 63, wv = tid >> 6;
  const float* mp = mask + (size_t)b * 2048;
  float v[8];
  #pragma unroll
  for (int i = 0; i < 8; i++) {
    int row = b * 2048 + tid * 8 + i;
    float s = 0.f;
    #pragma unroll
    for (int t = 0; t < 8; t++) s += part[(size_t)t * 16384 + row];
    v[i] = s + mp[tid * 8 + i];
  }
  float mx = -1e30f;
  #pragma unroll
  for (int i = 0; i < 8; i++) mx = fmaxf(mx, v[i]);
  __shared__ float red[4];
  #pragma unroll
  for (int o = 32; o; o >>= 1) mx = fmaxf(mx, __shfl_xor(mx, o));
  if (lane == 0) red[wv] = mx;
  __syncthreads();
  mx = fmaxf(fmaxf(red[0], red[1]), fmaxf(red[2], red[3]));
  __syncthreads();
  float s = 0.f;
  #pragma unroll
  for (int i = 0; i < 8; i++) { v[i] = expf(v[i] - mx); s += v[i]; }
  s = wredsum(s);
  if (lane == 0) red[wv] = s;
  __syncthreads();
  s = red[0] + red[1] + red[2] + red[3];
  float inv = 1.f / s;
  #pragma unroll
  for (int i = 0; i < 8; i++) w[(size_t)b * 2048 + tid * 8 + i] = v[i] * inv;
}

// ---------- tvp[b][sc][col] = sum_{s in chunk sc} w[b][s] * h[b][s][col] ----------
__global__ void taskvec_part(const u16* __restrict__ h, const float* __restrict__ w,
                             float* __restrict__ tvp) {
  int b = blockIdx.y, sc = blockIdx.z;
  int col = blockIdx.x * 256 + threadIdx.x;
  const u16* hp = h + ((size_t)b * 2048 + sc * 256) * 1024 + col;
  const float* wp = w + (size_t)b * 2048 + sc * 256;
  float a0 = 0.f, a1 = 0.f, a2 = 0.f, a3 = 0.f;
  for (int s = 0; s < 256; s += 4) {
    a0 += wp[s]     * bf2f(hp[(size_t)s * 1024]);
    a1 += wp[s + 1] * bf2f(hp[(size_t)(s + 1) * 1024]);
    a2 += wp[s + 2] * bf2f(hp[(size_t)(s + 2) * 1024]);
    a3 += wp[s + 3] * bf2f(hp[(size_t)(s + 3) * 1024]);
  }
  tvp[((size_t)b * 8 + sc) * 1024 + col] = (a0 + a1) + (a2 + a3);
}

// ---------- merged: reduce tvp -> tv (LDS) -> d[b][t] softmax -> bias2 ----------
__global__ void taskvec_dist(const float* __restrict__ tvp, const float* __restrict__ selW,
                             const float* __restrict__ selb, const float* __restrict__ pb2,
                             float* __restrict__ dvec, float* __restrict__ bias2) {
  int b = blockIdx.x, tid = threadIdx.x;
  int lane = tid & 63, wv = tid >> 6;
  __shared__ float tvs[1024];
  #pragma unroll
  for (int c4 = 0; c4 < 4; ++c4) {
    int col = c4 * 256 + tid;
    float s = 0.f;
    #pragma unroll
    for (int c = 0; c < 8; ++c) s += tvp[((size_t)b * 8 + c) * 1024 + col];
    tvs[col] = s;
  }
  __syncthreads();
  const float* sw = selW + (size_t)wv * 1024;
  float s = 0.f;
  #pragma unroll
  for (int j = 0; j < 16; j++) s += tvs[lane * 16 + j] * sw[lane * 16 + j];
  s = wredsum(s);
  __shared__ float lg[4];
  if (lane == 0) lg[wv] = s + selb[wv];
  __syncthreads();
  float m = fmaxf(fmaxf(lg[0], lg[1]), fmaxf(lg[2], lg[3]));
  float e0 = expf(lg[0] - m), e1 = expf(lg[1] - m), e2 = expf(lg[2] - m), e3 = expf(lg[3] - m);
  float inv = 1.f / (e0 + e1 + e2 + e3);
  float d0 = e0 * inv, d1 = e1 * inv, d2 = e2 * inv, d3 = e3 * inv;
  if (tid < 4) dvec[b * 4 + tid] = (tid == 0) ? d0 : (tid == 1) ? d1 : (tid == 2) ? d2 : d3;
  #pragma unroll
  for (int c = 0; c < 4; c++) {
    int n = c * 256 + tid;
    bias2[(size_t)b * 1024 + n] =
        d0 * pb2[n] + d1 * pb2[1024 + n] + d2 * pb2[2048 + n] + d3 * pb2[3072 + n];
  }
}

// ---------- row LayerNorm (H=1024) from bf16 x -> f32 out ----------
__global__ void ln_bf16_kernel(const u16* __restrict__ x, const float* __restrict__ g,
                               const float* __restrict__ bt, float* __restrict__ out) {
  int row = blockIdx.x, tid = threadIdx.x;
  int lane = tid & 63, wv = tid >> 6;
  ushort4 u = ((const ushort4*)(x + (size_t)row * 1024))[tid];
  float v0 = bf2f(u.x), v1 = bf2f(u.y), v2 = bf2f(u.z), v3 = bf2f(u.w);
  float s = v0 + v1 + v2 + v3;
  float q = v0 * v0 + v1 * v1 + v2 * v2 + v3 * v3;
  #pragma unroll
  for (int o = 32; o; o >>= 1) { s += __shfl_xor(s, o); q += __shfl_xor(q, o); }
  __shared__ float rs[4], rq[4];
  if (lane == 0) { rs[wv] = s; rq[wv] = q; }
  __syncthreads();
  s = rs[0] + rs[1] + rs[2] + rs[3];
  q = rq[0] + rq[1] + rq[2] + rq[3];
  float mu = s * (1.f / 1024.f);
  float var = q * (1.f / 1024.f) - mu * mu;
  float inv = 1.f / sqrtf(var + 1e-12f);
  const float4 gv = ((const float4*)g)[tid];
  const float4 bv = ((const float4*)bt)[tid];
  float4 o;
  o.x = gv.x * (v0 - mu) * inv + bv.x;
  o.y = gv.y * (v1 - mu) * inv + bv.y;
  o.z = gv.z * (v2 - mu) * inv + bv.z;
  o.w = gv.w * (v3 - mu) * inv + bv.w;
  ((float4*)(out + (size_t)row * 1024))[tid] = o;
}

extern "C" void kernel_launch(void* const* d_in, const int* in_sizes, int n_in,
                              void* d_out, int out_size, void* d_ws, size_t ws_size,
                              hipStream_t stream) {
  const float* hidden = (const float*)d_in[0];
  const float* input  = (const float*)d_in[1];
  const float* mask   = (const float*)d_in[2];
  const float* denseW = (const float*)d_in[3];
  const float* denseB = (const float*)d_in[4];
  const float* palW1  = (const float*)d_in[5];
  const float* palB1  = (const float*)d_in[6];
  const float* palW2  = (const float*)d_in[7];
  const float* palB2  = (const float*)d_in[8];
  const float* encW   = (const float*)d_in[9];
  const float* selW   = (const float*)d_in[11];
  const float* selB   = (const float*)d_in[12];
  const float* lnG    = (const float*)d_in[13];
  const float* lnB    = (const float*)d_in[14];

  char* ws = (char*)d_ws;
  u16*  hbf    = (u16*)(ws);                       // 32 MB  h (bf16), later x (bf16, in-place)
  u16*  lowbuf = (u16*)(ws + 33554432);            // 32 MB  hidden bf16 / low (scaled)
  u16*  wdt    = (u16*)(ws + 67108864);            // 2 MB   dense_W^T
  u16*  w1t    = (u16*)(ws + 69206016);            // 2 MB   W1cat^T  [(t,p)][h]
  u16*  w2t    = (u16*)(ws + 71303168);            // 2 MB   W2cat^T  [h][(t,p)]
  float* wts    = (float*)(ws + 73465856);
  float* dvec   = (float*)(ws + 73564160);
  float* bias2  = (float*)(ws + 73568256);
  float* tvp    = (float*)(ws + 73601024);         // 256 KB partials

  // logits partials live in d_out scratch (fully written by gemm_bt1, consumed by
  // softmax, overwritten by LN at the end)
  float* lgpart = (float*)d_out;                   // 8 x 16384 f32 = 512 KB

  cvt_f32_bf16<<<16384, 256, 0, stream>>>((const float4*)hidden, (ushort4*)lowbuf);
  transpose_cvt<<<dim3(32, 32, 1), dim3(32, 8), 0, stream>>>(denseW, wdt, 1024, 1024);
  transpose_cvt<<<dim3(8, 32, 4),  dim3(32, 8), 0, stream>>>(palW1, w1t, 1024, 256);
  transpose_cvt<<<dim3(32, 32, 1), dim3(32, 8), 0, stream>>>(palW2, w2t, 1024, 1024);

  gemm_bt1<<<1024, 256, 0, stream>>>(lowbuf, wdt, hbf, denseB, encW, lgpart);

  softmax_seq<<<8, 256, 0, stream>>>(lgpart, mask, wts);
  taskvec_part<<<dim3(4, 8, 8), 256, 0, stream>>>(hbf, wts, tvp);
  taskvec_dist<<<8, 256, 0, stream>>>(tvp, selW, selB, palB2, dvec, bias2);

  gemm_bt<2><<<1024, 256, 0, stream>>>(hbf, w1t, lowbuf, palB1, dvec, nullptr);
  gemm_bt<3><<<1024, 256, 0, stream>>>(lowbuf, w2t, hbf, bias2, input, hbf);

  ln_bf16_kernel<<<16384, 256, 0, stream>>>(hbf, lnG, lnB, (float*)d_out);
}